// Round 3
// baseline (1665.210 us; speedup 1.0000x reference)
//
#include <hip/hip_runtime.h>
#include <stdint.h>

#define N_NODES 50000
#define N_EDGES 800000
#define D_IN    128
#define D_HID   512
#define NPAD    50048   // 391 * 128

typedef __attribute__((ext_vector_type(8))) short short8;
typedef __attribute__((ext_vector_type(4))) float f32x4;

union Pack8 { unsigned short us[8]; uint4 v; };

__device__ __forceinline__ float bf2f(unsigned short u) {
    union { unsigned int i; float f; } v; v.i = ((unsigned int)u) << 16; return v.f;
}
__device__ __forceinline__ unsigned short f2bf(float f) {
    union { float f; unsigned int i; } v; v.f = f;
    unsigned int r = v.i + 0x7fffu + ((v.i >> 16) & 1u);
    return (unsigned short)(r >> 16);
}
// dtype-flagged scalar load: isf32 ? f32 : bf16
__device__ __forceinline__ float loadP(const void* p, long i, int isf) {
    return isf ? ((const float*)p)[i] : bf2f(((const unsigned short*)p)[i]);
}
__device__ __forceinline__ uint4 pack8(float4 f0, float4 f1) {
    Pack8 p;
    p.us[0] = f2bf(f0.x); p.us[1] = f2bf(f0.y); p.us[2] = f2bf(f0.z); p.us[3] = f2bf(f0.w);
    p.us[4] = f2bf(f1.x); p.us[5] = f2bf(f1.y); p.us[6] = f2bf(f1.z); p.us[7] = f2bf(f1.w);
    return p.v;
}

// ---- zero stats + detect dtype / int width ----
__global__ void k_init(const void* __restrict__ x, const int* __restrict__ ei,
                       float* __restrict__ stats, int* __restrict__ flags) {
    int t = threadIdx.x;                       // 1 block, 512 threads
    for (int i = t; i < 1280; i += 512) stats[i] = 0.f;
    if (t == 0) {
        const unsigned short* xu = (const unsigned short*)x;
        int isf = 0;
        for (int i = 0; i < 8192; i++)
            if (((xu[i] >> 7) & 0xFF) == 0xFF) { isf = 1; break; }
        flags[0] = isf;
        int i64 = 1;
        for (int k = 0; k < 64; k++)
            if (ei[2 * k + 1] != 0) { i64 = 0; break; }
        flags[1] = i64;
    }
}

// ---- transpose to N-major bf16: out[n*K + k] = (bf16) in[k*N + n] ----
__global__ void k_transpose(const void* __restrict__ in, unsigned short* __restrict__ out,
                            int K, int N, const int* __restrict__ flags) {
    int isf = flags[0];
    int idx = blockIdx.x * 256 + threadIdx.x;
    if (idx < K * N) {
        int k = idx / N, n = idx % N;
        out[n * K + k] = isf ? f2bf(((const float*)in)[idx])
                             : ((const unsigned short*)in)[idx];
    }
}

// ---- agg = (float)x for real rows, 0 for pad rows ----
__global__ void k_seed(const void* __restrict__ x, float* __restrict__ agg,
                       const int* __restrict__ flags) {
    int isf = flags[0];
    int i = blockIdx.x * 256 + threadIdx.x;
    if (i < NPAD * D_IN) agg[i] = (i < N_NODES * D_IN) ? loadP(x, i, isf) : 0.f;
}

// ---- scatter: agg[dst] += x[src] ----
__global__ __launch_bounds__(256) void k_scatter(const int* __restrict__ ei,
                                                 const void* __restrict__ x,
                                                 float* __restrict__ agg,
                                                 const int* __restrict__ flags) {
    int isf = flags[0], i64 = flags[1];
    int e = blockIdx.x * 8 + (threadIdx.x >> 5);
    int l = threadIdx.x & 31;
    int s, d;
    if (i64) { s = ei[2 * e]; d = ei[2 * N_EDGES + 2 * e]; }
    else     { s = ei[e];     d = ei[N_EDGES + e]; }
    s = min(max(s, 0), N_NODES - 1);
    d = min(max(d, 0), N_NODES - 1);
    float v0, v1, v2, v3;
    if (isf) {
        float4 xv = *(const float4*)((const float*)x + (size_t)s * D_IN + l * 4);
        v0 = xv.x; v1 = xv.y; v2 = xv.z; v3 = xv.w;
    } else {
        ushort4 xv = *(const ushort4*)((const unsigned short*)x + (size_t)s * D_IN + l * 4);
        v0 = bf2f(xv.x); v1 = bf2f(xv.y); v2 = bf2f(xv.z); v3 = bf2f(xv.w);
    }
    float* p = agg + (size_t)d * D_IN + l * 4;
    atomicAdd(p + 0, v0);
    atomicAdd(p + 1, v1);
    atomicAdd(p + 2, v2);
    atomicAdd(p + 3, v3);
}

// ---- pass A: GEMM1 (agg @ W1 + b1), column sums/sumsq only, no h1 store ----
__global__ __launch_bounds__(256) void k_g1stats(const float* __restrict__ agg,
                                                 const unsigned short* __restrict__ w1t,
                                                 const void* __restrict__ b1,
                                                 float* __restrict__ sum1,
                                                 float* __restrict__ sumsq1,
                                                 const int* __restrict__ flags) {
    __shared__ unsigned short ldsX[128 * 128];
    __shared__ unsigned short ldsW[128 * 128];
    int isf = flags[0];
    int t = threadIdx.x;
    int m0 = blockIdx.x * 128, n0 = blockIdx.y * 128;
    int r = t >> 1, half = t & 1;
#pragma unroll
    for (int i = 0; i < 8; i++) {
        int chunk = half * 8 + i;
        int sw = ((chunk ^ (r & 15)) * 8);
        const float* g = agg + (size_t)(m0 + r) * D_IN + chunk * 8;
        *(uint4*)(ldsX + r * 128 + sw) = pack8(*(const float4*)g, *(const float4*)(g + 4));
        *(uint4*)(ldsW + r * 128 + sw) = *(const uint4*)(w1t + (size_t)(n0 + r) * D_IN + chunk * 8);
    }
    __syncthreads();
    int wid = t >> 6, lane = t & 63;
    int wm = wid & 1, wn = wid >> 1;
    int quad = lane >> 4, l16 = lane & 15;
    f32x4 acc[4][4] = {};
#pragma unroll
    for (int ks = 0; ks < 4; ks++) {
        short8 af[4], bfr[4];
#pragma unroll
        for (int mt = 0; mt < 4; mt++)
            af[mt] = *(const short8*)(ldsX + (wm * 64 + mt * 16 + l16) * 128 + (((ks * 4 + quad) ^ l16) * 8));
#pragma unroll
        for (int nt = 0; nt < 4; nt++)
            bfr[nt] = *(const short8*)(ldsW + (wn * 64 + nt * 16 + l16) * 128 + (((ks * 4 + quad) ^ l16) * 8));
#pragma unroll
        for (int mt = 0; mt < 4; mt++)
#pragma unroll
            for (int nt = 0; nt < 4; nt++)
                acc[mt][nt] = __builtin_amdgcn_mfma_f32_16x16x32_bf16(af[mt], bfr[nt], acc[mt][nt], 0, 0, 0);
    }
#pragma unroll
    for (int nt = 0; nt < 4; nt++) {
        int n = n0 + wn * 64 + nt * 16 + l16;
        float bias = loadP(b1, n, isf);
        float s = 0.f, ss = 0.f;
#pragma unroll
        for (int mt = 0; mt < 4; mt++) {
            int Rb = m0 + wm * 64 + mt * 16 + quad * 4;
#pragma unroll
            for (int rg = 0; rg < 4; rg++) {
                if (Rb + rg < N_NODES) {   // exclude pad rows from BN stats
                    float z = acc[mt][nt][rg] + bias;
                    s += z; ss += z * z;
                }
            }
        }
        s += __shfl_xor(s, 16, 64); ss += __shfl_xor(ss, 16, 64);
        s += __shfl_xor(s, 32, 64); ss += __shfl_xor(ss, 32, 64);
        if (quad == 0) { atomicAdd(&sum1[n], s); atomicAdd(&sumsq1[n], ss); }
    }
}

// ---- pass B: fused GEMM1 -> BN1+ReLU -> GEMM2 (+b2), h2 f32 out, BN2 stats fused ----
__global__ __launch_bounds__(256) void k_fused(const float* __restrict__ agg,
                                               const unsigned short* __restrict__ w1t,
                                               const unsigned short* __restrict__ w2t,
                                               const void* __restrict__ b1,
                                               const void* __restrict__ b2,
                                               const void* __restrict__ g1,
                                               const void* __restrict__ bb1,
                                               const float* __restrict__ sum1,
                                               const float* __restrict__ sumsq1,
                                               float* __restrict__ h2,
                                               float* __restrict__ sum2,
                                               float* __restrict__ sumsq2,
                                               const int* __restrict__ flags) {
    __shared__ unsigned short bufXP[128 * 128];   // X tile, then P tile
    __shared__ unsigned short bufW[128 * 128];    // W1 tile, then W2 tile
    int isf = flags[0];
    int t = threadIdx.x;
    int m0 = blockIdx.x * 128;
    int r = t >> 1, half = t & 1;
    int wid = t >> 6, lane = t & 63;
    int wm = wid & 1, wn = wid >> 1;
    int quad = lane >> 4, l16 = lane & 15;
    f32x4 acc2[4][4] = {};
    for (int nb = 0; nb < 4; nb++) {
        __syncthreads();   // protect previous iteration's P / W2 reads
#pragma unroll
        for (int i = 0; i < 8; i++) {
            int chunk = half * 8 + i;
            int sw = ((chunk ^ (r & 15)) * 8);
            const float* g = agg + (size_t)(m0 + r) * D_IN + chunk * 8;
            *(uint4*)(bufXP + r * 128 + sw) = pack8(*(const float4*)g, *(const float4*)(g + 4));
            *(uint4*)(bufW + r * 128 + sw) = *(const uint4*)(w1t + (size_t)(nb * 128 + r) * D_IN + chunk * 8);
        }
        __syncthreads();
        f32x4 acc1[4][4] = {};
#pragma unroll
        for (int ks = 0; ks < 4; ks++) {
            short8 af[4], bfr[4];
#pragma unroll
            for (int mt = 0; mt < 4; mt++)
                af[mt] = *(const short8*)(bufXP + (wm * 64 + mt * 16 + l16) * 128 + (((ks * 4 + quad) ^ l16) * 8));
#pragma unroll
            for (int nt = 0; nt < 4; nt++)
                bfr[nt] = *(const short8*)(bufW + (wn * 64 + nt * 16 + l16) * 128 + (((ks * 4 + quad) ^ l16) * 8));
#pragma unroll
            for (int mt = 0; mt < 4; mt++)
#pragma unroll
                for (int nt = 0; nt < 4; nt++)
                    acc1[mt][nt] = __builtin_amdgcn_mfma_f32_16x16x32_bf16(af[mt], bfr[nt], acc1[mt][nt], 0, 0, 0);
        }
        __syncthreads();   // done reading X and W1
        // BN1 + ReLU -> P (bf16) into bufXP; stage W2 into bufW
#pragma unroll
        for (int nt = 0; nt < 4; nt++) {
            int nl = wn * 64 + nt * 16 + l16;     // local col in P
            int n1 = nb * 128 + nl;
            float mz = sum1[n1] * (1.f / N_NODES);
            float vz = sumsq1[n1] * (1.f / N_NODES) - mz * mz;
            float inv = rsqrtf(fmaxf(vz, 0.f) + 1e-5f);
            float A = loadP(g1, n1, isf) * inv;
            float C = loadP(bb1, n1, isf) - mz * A + loadP(b1, n1, isf) * A;
            int ccw = nl >> 3, cl = nl & 7;
#pragma unroll
            for (int mt = 0; mt < 4; mt++)
#pragma unroll
                for (int rg = 0; rg < 4; rg++) {
                    int R = wm * 64 + mt * 16 + quad * 4 + rg;
                    float z = fmaxf(acc1[mt][nt][rg] * A + C, 0.f);
                    bufXP[R * 128 + ((ccw ^ (R & 15)) * 8) + cl] = f2bf(z);
                }
        }
#pragma unroll
        for (int i = 0; i < 8; i++) {
            int chunk = half * 8 + i;
            *(uint4*)(bufW + r * 128 + ((chunk ^ (r & 15)) * 8)) =
                *(const uint4*)(w2t + (size_t)r * D_HID + nb * 128 + chunk * 8);
        }
        __syncthreads();
#pragma unroll
        for (int ks = 0; ks < 4; ks++) {
            short8 af[4], bfr[4];
#pragma unroll
            for (int mt = 0; mt < 4; mt++)
                af[mt] = *(const short8*)(bufXP + (wm * 64 + mt * 16 + l16) * 128 + (((ks * 4 + quad) ^ l16) * 8));
#pragma unroll
            for (int nt = 0; nt < 4; nt++)
                bfr[nt] = *(const short8*)(bufW + (wn * 64 + nt * 16 + l16) * 128 + (((ks * 4 + quad) ^ l16) * 8));
#pragma unroll
            for (int mt = 0; mt < 4; mt++)
#pragma unroll
                for (int nt = 0; nt < 4; nt++)
                    acc2[mt][nt] = __builtin_amdgcn_mfma_f32_16x16x32_bf16(af[mt], bfr[nt], acc2[mt][nt], 0, 0, 0);
        }
    }
    // epilogue: z2 = acc2 + b2 -> h2 (f32, overwrites agg rows of this block); BN2 stats
#pragma unroll
    for (int nt = 0; nt < 4; nt++) {
        int n = wn * 64 + nt * 16 + l16;
        float bias = loadP(b2, n, isf);
        float s = 0.f, ss = 0.f;
#pragma unroll
        for (int mt = 0; mt < 4; mt++) {
            int Rb = m0 + wm * 64 + mt * 16 + quad * 4;
#pragma unroll
            for (int rg = 0; rg < 4; rg++) {
                float z = acc2[mt][nt][rg] + bias;
                h2[(size_t)(Rb + rg) * D_IN + n] = z;
                if (Rb + rg < N_NODES) { s += z; ss += z * z; }
            }
        }
        s += __shfl_xor(s, 16, 64); ss += __shfl_xor(ss, 16, 64);
        s += __shfl_xor(s, 32, 64); ss += __shfl_xor(ss, 32, 64);
        if (quad == 0) { atomicAdd(&sum2[n], s); atomicAdd(&sumsq2[n], ss); }
    }
}

// ---- BN2 + ReLU + residual + LayerNorm -> out ----
__global__ __launch_bounds__(256) void k_final(const float* __restrict__ h2,
                                               const void* __restrict__ x,
                                               const float* __restrict__ sum2,
                                               const float* __restrict__ sumsq2,
                                               const void* __restrict__ g2,
                                               const void* __restrict__ bb2,
                                               const void* __restrict__ lng,
                                               const void* __restrict__ lnb,
                                               void* __restrict__ out,
                                               const int* __restrict__ flags) {
    int isf = flags[0];
    __shared__ float a2s[D_IN], c2s[D_IN];
    int t = threadIdx.x;
    if (t < D_IN) {
        float m = sum2[t] * (1.f / N_NODES);
        float v = sumsq2[t] * (1.f / N_NODES) - m * m;
        float inv = rsqrtf(fmaxf(v, 0.f) + 1e-5f);
        float a = loadP(g2, t, isf) * inv;
        a2s[t] = a;
        c2s[t] = loadP(bb2, t, isf) - m * a;
    }
    __syncthreads();
    int w = t >> 6, lane = t & 63;
    int row = blockIdx.x * 4 + w;
    if (row >= N_NODES) return;
    size_t base = (size_t)row * D_IN;
    float o0 = fmaxf(a2s[lane] * h2[base + lane] + c2s[lane], 0.f) + loadP(x, base + lane, isf);
    float o1 = fmaxf(a2s[lane + 64] * h2[base + 64 + lane] + c2s[lane + 64], 0.f) + loadP(x, base + 64 + lane, isf);
    float s = o0 + o1, ss = o0 * o0 + o1 * o1;
#pragma unroll
    for (int m = 1; m < 64; m <<= 1) {
        s += __shfl_xor(s, m, 64);
        ss += __shfl_xor(ss, m, 64);
    }
    float mean = s * (1.f / D_IN);
    float var = ss * (1.f / D_IN) - mean * mean;
    float inv = rsqrtf(fmaxf(var, 0.f) + 1e-5f);
    float r0 = (o0 - mean) * inv * loadP(lng, lane, isf) + loadP(lnb, lane, isf);
    float r1 = (o1 - mean) * inv * loadP(lng, lane + 64, isf) + loadP(lnb, lane + 64, isf);
    if (isf) {
        ((float*)out)[base + lane] = r0;
        ((float*)out)[base + 64 + lane] = r1;
    } else {
        ((unsigned short*)out)[base + lane] = f2bf(r0);
        ((unsigned short*)out)[base + 64 + lane] = f2bf(r1);
    }
}

extern "C" void kernel_launch(void* const* d_in, const int* in_sizes, int n_in,
                              void* d_out, int out_size, void* d_ws, size_t ws_size,
                              hipStream_t stream) {
    const void* x    = d_in[0];
    const int*  ei   = (const int*)d_in[1];
    const void* W1   = d_in[2];
    const void* b1   = d_in[3];
    const void* bn1g = d_in[4];
    const void* bn1b = d_in[5];
    const void* W2   = d_in[6];
    const void* b2   = d_in[7];
    const void* bn2g = d_in[8];
    const void* bn2b = d_in[9];
    const void* lng  = d_in[10];
    const void* lnb  = d_in[11];

    // workspace layout — total ~25.9 MB
    char* ws = (char*)d_ws;
    float* stats  = (float*)ws;              // 1280 f32
    float* sum1   = stats;
    float* sumsq1 = stats + 512;
    float* sum2   = stats + 1024;
    float* sumsq2 = stats + 1152;
    int*   flags  = (int*)(ws + 5120);       // 2 ints
    unsigned short* w1t = (unsigned short*)(ws + 8192);            // [512][128] bf16
    unsigned short* w2t = (unsigned short*)(ws + 8192 + 131072);   // [128][512] bf16
    float* agg = (float*)(ws + 270336);      // NPAD*128 f32, reused as h2
    float* h2  = agg;

    k_init<<<1, 512, 0, stream>>>(x, ei, stats, flags);
    k_transpose<<<256, 256, 0, stream>>>(W1, w1t, D_IN, D_HID, flags);
    k_transpose<<<256, 256, 0, stream>>>(W2, w2t, D_HID, D_IN, flags);
    k_seed<<<(NPAD * D_IN) / 256, 256, 0, stream>>>(x, agg, flags);
    k_scatter<<<N_EDGES / 8, 256, 0, stream>>>(ei, x, agg, flags);
    k_g1stats<<<dim3(NPAD / 128, D_HID / 128), 256, 0, stream>>>(agg, w1t, b1, sum1, sumsq1, flags);
    k_fused<<<NPAD / 128, 256, 0, stream>>>(agg, w1t, w2t, b1, b2, bn1g, bn1b,
                                            sum1, sumsq1, h2, sum2, sumsq2, flags);
    k_final<<<(N_NODES + 3) / 4, 256, 0, stream>>>(h2, x, sum2, sumsq2, bn2g, bn2b, lng, lnb, d_out, flags);
}

// Round 4
// 513.672 us; speedup vs baseline: 3.2418x; 3.2418x over previous
//
#include <hip/hip_runtime.h>
#include <stdint.h>

#define N_NODES 50000
#define N_EDGES 800000
#define D_IN    128
#define D_HID   512
#define NPAD    50048   // 391 * 128

typedef __attribute__((ext_vector_type(8))) short short8;
typedef __attribute__((ext_vector_type(4))) float f32x4;

union Pack8 { unsigned short us[8]; uint4 v; };

__device__ __forceinline__ float bf2f(unsigned short u) {
    union { unsigned int i; float f; } v; v.i = ((unsigned int)u) << 16; return v.f;
}
__device__ __forceinline__ unsigned short f2bf(float f) {
    union { float f; unsigned int i; } v; v.f = f;
    unsigned int r = v.i + 0x7fffu + ((v.i >> 16) & 1u);
    return (unsigned short)(r >> 16);
}
__device__ __forceinline__ float loadP(const void* p, long i, int isf) {
    return isf ? ((const float*)p)[i] : bf2f(((const unsigned short*)p)[i]);
}
__device__ __forceinline__ uint4 pack8(float4 f0, float4 f1) {
    Pack8 p;
    p.us[0] = f2bf(f0.x); p.us[1] = f2bf(f0.y); p.us[2] = f2bf(f0.z); p.us[3] = f2bf(f0.w);
    p.us[4] = f2bf(f1.x); p.us[5] = f2bf(f1.y); p.us[6] = f2bf(f1.z); p.us[7] = f2bf(f1.w);
    return p.v;
}

// ---- detect dtype (f32 vs bf16) and edge-index width (i64 vs i32), parallel ----
__global__ void k_detect(const void* __restrict__ x, const int* __restrict__ ei,
                         int* __restrict__ flags) {
    __shared__ int sh[2];
    int t = threadIdx.x;
    if (t == 0) { sh[0] = 0; sh[1] = 1; }
    __syncthreads();
    const unsigned short* xu = (const unsigned short*)x;
    for (int i = t; i < 8192; i += 256)
        if (((xu[i] >> 7) & 0xFF) == 0xFF) sh[0] = 1;   // benign race
    for (int k = t; k < 64; k += 256)
        if (ei[2 * k + 1] != 0) sh[1] = 0;
    __syncthreads();
    if (t == 0) { flags[0] = sh[0]; flags[1] = sh[1]; }
}

// ---- zero stats (1280 f32) + counts (50000 int) ----
__global__ void k_zero(float* __restrict__ stats, int* __restrict__ counts) {
    int i = blockIdx.x * 256 + threadIdx.x;
    if (i < 1280) stats[i] = 0.f;
    else if (i < 1280 + N_NODES) counts[i - 1280] = 0;
}

// ---- transpose to N-major bf16 ----
__global__ void k_transpose(const void* __restrict__ in, unsigned short* __restrict__ out,
                            int K, int N, const int* __restrict__ flags) {
    int isf = flags[0];
    int idx = blockIdx.x * 256 + threadIdx.x;
    if (idx < K * N) {
        int k = idx / N, n = idx % N;
        out[n * K + k] = isf ? f2bf(((const float*)in)[idx])
                             : ((const unsigned short*)in)[idx];
    }
}

// ---- CSR step 1: count in-degree ----
__global__ void k_count(const int* __restrict__ ei, int* __restrict__ counts,
                        const int* __restrict__ flags) {
    int i64 = flags[1];
    int e = blockIdx.x * 256 + threadIdx.x;
    int d = i64 ? ei[2 * N_EDGES + 2 * e] : ei[N_EDGES + e];
    d = min(max(d, 0), N_NODES - 1);
    atomicAdd(&counts[d], 1);
}

// ---- CSR step 2: exclusive scan -> rowptr; counts becomes cursor ----
__global__ __launch_bounds__(1024) void k_scan(int* __restrict__ counts,
                                               int* __restrict__ rowptr) {
    __shared__ int a[1024], b[1024];
    int t = threadIdx.x;
    int lo = t * 49, hi = min(lo + 49, N_NODES);
    int s = 0;
    for (int i = lo; i < hi; i++) s += counts[i];
    a[t] = s;
    __syncthreads();
    int* src = a; int* dst = b;
    for (int off = 1; off < 1024; off <<= 1) {
        dst[t] = src[t] + ((t >= off) ? src[t - off] : 0);
        __syncthreads();
        int* tmp = src; src = dst; dst = tmp;
    }
    int excl = src[t] - s;
    int running = excl;
    for (int i = lo; i < hi; i++) {
        int c = counts[i];
        rowptr[i] = running;
        counts[i] = running;    // counts array now = cursor
        running += c;
    }
    if (t == 1023) rowptr[N_NODES] = src[1023];
}

// ---- CSR step 3: fill buckets with src ids ----
__global__ void k_fill(const int* __restrict__ ei, int* __restrict__ cursor,
                       int* __restrict__ bucket, const int* __restrict__ flags) {
    int i64 = flags[1];
    int e = blockIdx.x * 256 + threadIdx.x;
    int s, d;
    if (i64) { s = ei[2 * e]; d = ei[2 * N_EDGES + 2 * e]; }
    else     { s = ei[e];     d = ei[N_EDGES + e]; }
    s = min(max(s, 0), N_NODES - 1);
    d = min(max(d, 0), N_NODES - 1);
    int pos = atomicAdd(&cursor[d], 1);
    bucket[pos] = s;
}

// ---- gather-sum: agg[row] = x[row] + sum_{e:dst=row} x[src[e]]; pad rows = 0 ----
__global__ __launch_bounds__(256) void k_gather(const int* __restrict__ rowptr,
                                                const int* __restrict__ bucket,
                                                const void* __restrict__ x,
                                                float* __restrict__ agg,
                                                const int* __restrict__ flags) {
    int isf = flags[0];
    int w = threadIdx.x >> 6, lane = threadIdx.x & 63;
    int row = blockIdx.x * 4 + w;          // grid = NPAD/4, exact
    float a0 = 0.f, a1 = 0.f;
    if (row < N_NODES) {
        int beg = rowptr[row], end = rowptr[row + 1];
        if (isf) {
            float2 v = *(const float2*)((const float*)x + (size_t)row * D_IN + lane * 2);
            a0 = v.x; a1 = v.y;
            for (int j = beg; j < end; j++) {
                int s = bucket[j];
                float2 n = *(const float2*)((const float*)x + (size_t)s * D_IN + lane * 2);
                a0 += n.x; a1 += n.y;
            }
        } else {
            unsigned int u = ((const unsigned int*)x)[(size_t)row * 64 + lane];
            a0 = bf2f(u & 0xffff); a1 = bf2f(u >> 16);
            for (int j = beg; j < end; j++) {
                int s = bucket[j];
                unsigned int n = ((const unsigned int*)x)[(size_t)s * 64 + lane];
                a0 += bf2f(n & 0xffff); a1 += bf2f(n >> 16);
            }
        }
    }
    *(float2*)(agg + (size_t)row * D_IN + lane * 2) = make_float2(a0, a1);
}

// ---- pass A: GEMM1 column stats (X tile staged once, loop 4 W-tiles) ----
__global__ __launch_bounds__(256) void k_g1stats(const float* __restrict__ agg,
                                                 const unsigned short* __restrict__ w1t,
                                                 const void* __restrict__ b1,
                                                 float* __restrict__ sum1,
                                                 float* __restrict__ sumsq1,
                                                 const int* __restrict__ flags) {
    __shared__ unsigned short ldsX[128 * 128];
    __shared__ unsigned short ldsW[128 * 128];
    int isf = flags[0];
    int t = threadIdx.x;
    int m0 = blockIdx.x * 128;
    int r = t >> 1, half = t & 1;
#pragma unroll
    for (int i = 0; i < 8; i++) {
        int chunk = half * 8 + i;
        int sw = ((chunk ^ (r & 15)) * 8);
        const float* g = agg + (size_t)(m0 + r) * D_IN + chunk * 8;
        *(uint4*)(ldsX + r * 128 + sw) = pack8(*(const float4*)g, *(const float4*)(g + 4));
    }
    int wid = t >> 6, lane = t & 63;
    int wm = wid & 1, wn = wid >> 1;
    int quad = lane >> 4, l16 = lane & 15;
    for (int nb = 0; nb < 4; nb++) {
        __syncthreads();   // X staged / prior W readers done
#pragma unroll
        for (int i = 0; i < 8; i++) {
            int chunk = half * 8 + i;
            *(uint4*)(ldsW + r * 128 + ((chunk ^ (r & 15)) * 8)) =
                *(const uint4*)(w1t + (size_t)(nb * 128 + r) * D_IN + chunk * 8);
        }
        __syncthreads();
        f32x4 acc[4][4] = {};
#pragma unroll
        for (int ks = 0; ks < 4; ks++) {
            short8 af[4], bfr[4];
#pragma unroll
            for (int mt = 0; mt < 4; mt++)
                af[mt] = *(const short8*)(ldsX + (wm * 64 + mt * 16 + l16) * 128 + (((ks * 4 + quad) ^ l16) * 8));
#pragma unroll
            for (int nt = 0; nt < 4; nt++)
                bfr[nt] = *(const short8*)(ldsW + (wn * 64 + nt * 16 + l16) * 128 + (((ks * 4 + quad) ^ l16) * 8));
#pragma unroll
            for (int mt = 0; mt < 4; mt++)
#pragma unroll
                for (int nt = 0; nt < 4; nt++)
                    acc[mt][nt] = __builtin_amdgcn_mfma_f32_16x16x32_bf16(af[mt], bfr[nt], acc[mt][nt], 0, 0, 0);
        }
#pragma unroll
        for (int nt = 0; nt < 4; nt++) {
            int n = nb * 128 + wn * 64 + nt * 16 + l16;
            float bias = loadP(b1, n, isf);
            float s = 0.f, ss = 0.f;
#pragma unroll
            for (int mt = 0; mt < 4; mt++) {
                int Rb = m0 + wm * 64 + mt * 16 + quad * 4;
#pragma unroll
                for (int rg = 0; rg < 4; rg++) {
                    if (Rb + rg < N_NODES) {
                        float z = acc[mt][nt][rg] + bias;
                        s += z; ss += z * z;
                    }
                }
            }
            s += __shfl_xor(s, 16, 64); ss += __shfl_xor(ss, 16, 64);
            s += __shfl_xor(s, 32, 64); ss += __shfl_xor(ss, 32, 64);
            if (quad == 0) { atomicAdd(&sum1[n], s); atomicAdd(&sumsq1[n], ss); }
        }
    }
}

// ---- pass B: fused GEMM1 -> BN1+ReLU -> GEMM2 (+b2), h2 f32, BN2 stats fused ----
__global__ __launch_bounds__(256) void k_fused(const float* __restrict__ agg,
                                               const unsigned short* __restrict__ w1t,
                                               const unsigned short* __restrict__ w2t,
                                               const void* __restrict__ b1,
                                               const void* __restrict__ b2,
                                               const void* __restrict__ g1,
                                               const void* __restrict__ bb1,
                                               const float* __restrict__ sum1,
                                               const float* __restrict__ sumsq1,
                                               float* __restrict__ h2,
                                               float* __restrict__ sum2,
                                               float* __restrict__ sumsq2,
                                               const int* __restrict__ flags) {
    __shared__ unsigned short bufXP[128 * 128];
    __shared__ unsigned short bufW[128 * 128];
    int isf = flags[0];
    int t = threadIdx.x;
    int m0 = blockIdx.x * 128;
    int r = t >> 1, half = t & 1;
    int wid = t >> 6, lane = t & 63;
    int wm = wid & 1, wn = wid >> 1;
    int quad = lane >> 4, l16 = lane & 15;
    f32x4 acc2[4][4] = {};
    for (int nb = 0; nb < 4; nb++) {
        __syncthreads();
#pragma unroll
        for (int i = 0; i < 8; i++) {
            int chunk = half * 8 + i;
            int sw = ((chunk ^ (r & 15)) * 8);
            const float* g = agg + (size_t)(m0 + r) * D_IN + chunk * 8;
            *(uint4*)(bufXP + r * 128 + sw) = pack8(*(const float4*)g, *(const float4*)(g + 4));
            *(uint4*)(bufW + r * 128 + sw) = *(const uint4*)(w1t + (size_t)(nb * 128 + r) * D_IN + chunk * 8);
        }
        __syncthreads();
        f32x4 acc1[4][4] = {};
#pragma unroll
        for (int ks = 0; ks < 4; ks++) {
            short8 af[4], bfr[4];
#pragma unroll
            for (int mt = 0; mt < 4; mt++)
                af[mt] = *(const short8*)(bufXP + (wm * 64 + mt * 16 + l16) * 128 + (((ks * 4 + quad) ^ l16) * 8));
#pragma unroll
            for (int nt = 0; nt < 4; nt++)
                bfr[nt] = *(const short8*)(bufW + (wn * 64 + nt * 16 + l16) * 128 + (((ks * 4 + quad) ^ l16) * 8));
#pragma unroll
            for (int mt = 0; mt < 4; mt++)
#pragma unroll
                for (int nt = 0; nt < 4; nt++)
                    acc1[mt][nt] = __builtin_amdgcn_mfma_f32_16x16x32_bf16(af[mt], bfr[nt], acc1[mt][nt], 0, 0, 0);
        }
        __syncthreads();
#pragma unroll
        for (int nt = 0; nt < 4; nt++) {
            int nl = wn * 64 + nt * 16 + l16;
            int n1 = nb * 128 + nl;
            float mz = sum1[n1] * (1.f / N_NODES);
            float vz = sumsq1[n1] * (1.f / N_NODES) - mz * mz;
            float inv = rsqrtf(fmaxf(vz, 0.f) + 1e-5f);
            float A = loadP(g1, n1, isf) * inv;
            float C = loadP(bb1, n1, isf) - mz * A + loadP(b1, n1, isf) * A;
            int ccw = nl >> 3, cl = nl & 7;
#pragma unroll
            for (int mt = 0; mt < 4; mt++)
#pragma unroll
                for (int rg = 0; rg < 4; rg++) {
                    int R = wm * 64 + mt * 16 + quad * 4 + rg;
                    float z = fmaxf(acc1[mt][nt][rg] * A + C, 0.f);
                    bufXP[R * 128 + ((ccw ^ (R & 15)) * 8) + cl] = f2bf(z);
                }
        }
#pragma unroll
        for (int i = 0; i < 8; i++) {
            int chunk = half * 8 + i;
            *(uint4*)(bufW + r * 128 + ((chunk ^ (r & 15)) * 8)) =
                *(const uint4*)(w2t + (size_t)r * D_HID + nb * 128 + chunk * 8);
        }
        __syncthreads();
#pragma unroll
        for (int ks = 0; ks < 4; ks++) {
            short8 af[4], bfr[4];
#pragma unroll
            for (int mt = 0; mt < 4; mt++)
                af[mt] = *(const short8*)(bufXP + (wm * 64 + mt * 16 + l16) * 128 + (((ks * 4 + quad) ^ l16) * 8));
#pragma unroll
            for (int nt = 0; nt < 4; nt++)
                bfr[nt] = *(const short8*)(bufW + (wn * 64 + nt * 16 + l16) * 128 + (((ks * 4 + quad) ^ l16) * 8));
#pragma unroll
            for (int mt = 0; mt < 4; mt++)
#pragma unroll
                for (int nt = 0; nt < 4; nt++)
                    acc2[mt][nt] = __builtin_amdgcn_mfma_f32_16x16x32_bf16(af[mt], bfr[nt], acc2[mt][nt], 0, 0, 0);
        }
    }
#pragma unroll
    for (int nt = 0; nt < 4; nt++) {
        int n = wn * 64 + nt * 16 + l16;
        float bias = loadP(b2, n, isf);
        float s = 0.f, ss = 0.f;
#pragma unroll
        for (int mt = 0; mt < 4; mt++) {
            int Rb = m0 + wm * 64 + mt * 16 + quad * 4;
#pragma unroll
            for (int rg = 0; rg < 4; rg++) {
                float z = acc2[mt][nt][rg] + bias;
                h2[(size_t)(Rb + rg) * D_IN + n] = z;
                if (Rb + rg < N_NODES) { s += z; ss += z * z; }
            }
        }
        s += __shfl_xor(s, 16, 64); ss += __shfl_xor(ss, 16, 64);
        s += __shfl_xor(s, 32, 64); ss += __shfl_xor(ss, 32, 64);
        if (quad == 0) { atomicAdd(&sum2[n], s); atomicAdd(&sumsq2[n], ss); }
    }
}

// ---- BN2 + ReLU + residual + LayerNorm -> out ----
__global__ __launch_bounds__(256) void k_final(const float* __restrict__ h2,
                                               const void* __restrict__ x,
                                               const float* __restrict__ sum2,
                                               const float* __restrict__ sumsq2,
                                               const void* __restrict__ g2,
                                               const void* __restrict__ bb2,
                                               const void* __restrict__ lng,
                                               const void* __restrict__ lnb,
                                               void* __restrict__ out,
                                               const int* __restrict__ flags) {
    int isf = flags[0];
    __shared__ float a2s[D_IN], c2s[D_IN];
    int t = threadIdx.x;
    if (t < D_IN) {
        float m = sum2[t] * (1.f / N_NODES);
        float v = sumsq2[t] * (1.f / N_NODES) - m * m;
        float inv = rsqrtf(fmaxf(v, 0.f) + 1e-5f);
        float a = loadP(g2, t, isf) * inv;
        a2s[t] = a;
        c2s[t] = loadP(bb2, t, isf) - m * a;
    }
    __syncthreads();
    int w = t >> 6, lane = t & 63;
    int row = blockIdx.x * 4 + w;
    if (row >= N_NODES) return;
    size_t base = (size_t)row * D_IN;
    float o0 = fmaxf(a2s[lane] * h2[base + lane] + c2s[lane], 0.f) + loadP(x, base + lane, isf);
    float o1 = fmaxf(a2s[lane + 64] * h2[base + 64 + lane] + c2s[lane + 64], 0.f) + loadP(x, base + 64 + lane, isf);
    float s = o0 + o1, ss = o0 * o0 + o1 * o1;
#pragma unroll
    for (int m = 1; m < 64; m <<= 1) {
        s += __shfl_xor(s, m, 64);
        ss += __shfl_xor(ss, m, 64);
    }
    float mean = s * (1.f / D_IN);
    float var = ss * (1.f / D_IN) - mean * mean;
    float inv = rsqrtf(fmaxf(var, 0.f) + 1e-5f);
    float r0 = (o0 - mean) * inv * loadP(lng, lane, isf) + loadP(lnb, lane, isf);
    float r1 = (o1 - mean) * inv * loadP(lng, lane + 64, isf) + loadP(lnb, lane + 64, isf);
    if (isf) {
        ((float*)out)[base + lane] = r0;
        ((float*)out)[base + 64 + lane] = r1;
    } else {
        ((unsigned short*)out)[base + lane] = f2bf(r0);
        ((unsigned short*)out)[base + 64 + lane] = f2bf(r1);
    }
}

extern "C" void kernel_launch(void* const* d_in, const int* in_sizes, int n_in,
                              void* d_out, int out_size, void* d_ws, size_t ws_size,
                              hipStream_t stream) {
    const void* x    = d_in[0];
    const int*  ei   = (const int*)d_in[1];
    const void* W1   = d_in[2];
    const void* b1   = d_in[3];
    const void* bn1g = d_in[4];
    const void* bn1b = d_in[5];
    const void* W2   = d_in[6];
    const void* b2   = d_in[7];
    const void* bn2g = d_in[8];
    const void* bn2b = d_in[9];
    const void* lng  = d_in[10];
    const void* lnb  = d_in[11];

    // workspace layout (~29.5 MB)
    char* ws = (char*)d_ws;
    float* stats  = (float*)ws;                       // 1280 f32
    float* sum1   = stats;
    float* sumsq1 = stats + 512;
    float* sum2   = stats + 1024;
    float* sumsq2 = stats + 1152;
    int*   flags  = (int*)(ws + 5120);
    int*   rowptr = (int*)(ws + 8192);                // 50001 ints
    int*   cursor = (int*)(ws + 212992);              // 50000 ints (counts, then cursor)
    unsigned short* w1t = (unsigned short*)(ws + 417792);   // [512][128] bf16
    unsigned short* w2t = (unsigned short*)(ws + 548864);   // [128][512] bf16
    int*   bucket = (int*)(ws + 679936);              // 800000 ints
    float* agg    = (float*)(ws + 3879936);           // NPAD*128 f32, reused as h2
    float* h2     = agg;

    k_detect<<<1, 256, 0, stream>>>(x, ei, flags);
    k_zero<<<(1280 + N_NODES + 255) / 256, 256, 0, stream>>>(stats, cursor);
    k_transpose<<<256, 256, 0, stream>>>(W1, w1t, D_IN, D_HID, flags);
    k_transpose<<<256, 256, 0, stream>>>(W2, w2t, D_HID, D_IN, flags);
    k_count<<<N_EDGES / 256, 256, 0, stream>>>(ei, cursor, flags);
    k_scan<<<1, 1024, 0, stream>>>(cursor, rowptr);
    k_fill<<<N_EDGES / 256, 256, 0, stream>>>(ei, cursor, bucket, flags);
    k_gather<<<NPAD / 4, 256, 0, stream>>>(rowptr, bucket, x, agg, flags);
    k_g1stats<<<NPAD / 128, 256, 0, stream>>>(agg, w1t, b1, sum1, sumsq1, flags);
    k_fused<<<NPAD / 128, 256, 0, stream>>>(agg, w1t, w2t, b1, b2, bn1g, bn1b,
                                            sum1, sumsq1, h2, sum2, sumsq2, flags);
    k_final<<<(N_NODES + 3) / 4, 256, 0, stream>>>(h2, x, sum2, sumsq2, bn2g, bn2b, lng, lnb, d_out, flags);
}

// Round 5
// 412.181 us; speedup vs baseline: 4.0400x; 1.2462x over previous
//
#include <hip/hip_runtime.h>
#include <stdint.h>

#define N_NODES 50000
#define N_EDGES 800000
#define D_IN    128
#define D_HID   512
#define NPAD    50048   // 391 * 128
#define SCAN_NB 196     // ceil(50000/256)

typedef __attribute__((ext_vector_type(8))) short short8;
typedef __attribute__((ext_vector_type(4))) float f32x4;

union Pack8 { unsigned short us[8]; uint4 v; };

__device__ __forceinline__ float bf2f(unsigned short u) {
    union { unsigned int i; float f; } v; v.i = ((unsigned int)u) << 16; return v.f;
}
__device__ __forceinline__ unsigned short f2bf(float f) {
    union { float f; unsigned int i; } v; v.f = f;
    unsigned int r = v.i + 0x7fffu + ((v.i >> 16) & 1u);
    return (unsigned short)(r >> 16);
}
__device__ __forceinline__ float loadP(const void* p, long i, int isf) {
    return isf ? ((const float*)p)[i] : bf2f(((const unsigned short*)p)[i]);
}
__device__ __forceinline__ uint4 pack8(float4 f0, float4 f1) {
    Pack8 p;
    p.us[0] = f2bf(f0.x); p.us[1] = f2bf(f0.y); p.us[2] = f2bf(f0.z); p.us[3] = f2bf(f0.w);
    p.us[4] = f2bf(f1.x); p.us[5] = f2bf(f1.y); p.us[6] = f2bf(f1.z); p.us[7] = f2bf(f1.w);
    return p.v;
}

// ---- detect dtype (f32 vs bf16) and edge-index width (i64 vs i32) ----
__global__ void k_detect(const void* __restrict__ x, const int* __restrict__ ei,
                         int* __restrict__ flags) {
    __shared__ int sh[2];
    int t = threadIdx.x;
    if (t == 0) { sh[0] = 0; sh[1] = 1; }
    __syncthreads();
    const unsigned short* xu = (const unsigned short*)x;
    for (int i = t; i < 8192; i += 256)
        if (((xu[i] >> 7) & 0xFF) == 0xFF) sh[0] = 1;   // benign race
    for (int k = t; k < 64; k += 256)
        if (ei[2 * k + 1] != 0) sh[1] = 0;
    __syncthreads();
    if (t == 0) { flags[0] = sh[0]; flags[1] = sh[1]; }
}

// ---- zero stats (1280 f32) + counts (50000 int) ----
__global__ void k_zero(float* __restrict__ stats, int* __restrict__ counts) {
    int i = blockIdx.x * 256 + threadIdx.x;
    if (i < 1280) stats[i] = 0.f;
    else if (i < 1280 + N_NODES) counts[i - 1280] = 0;
}

// ---- transpose to N-major bf16 ----
__global__ void k_transpose(const void* __restrict__ in, unsigned short* __restrict__ out,
                            int K, int N, const int* __restrict__ flags) {
    int isf = flags[0];
    int idx = blockIdx.x * 256 + threadIdx.x;
    if (idx < K * N) {
        int k = idx / N, n = idx % N;
        out[n * K + k] = isf ? f2bf(((const float*)in)[idx])
                             : ((const unsigned short*)in)[idx];
    }
}

// ---- CSR step 1: count in-degree ----
__global__ void k_count(const int* __restrict__ ei, int* __restrict__ counts,
                        const int* __restrict__ flags) {
    int i64 = flags[1];
    int e = blockIdx.x * 256 + threadIdx.x;
    int d = i64 ? ei[2 * N_EDGES + 2 * e] : ei[N_EDGES + e];
    d = min(max(d, 0), N_NODES - 1);
    atomicAdd(&counts[d], 1);
}

// ---- CSR step 2a: per-block exclusive scan; block sums -> partials ----
__global__ __launch_bounds__(256) void k_scan_block(const int* __restrict__ counts,
                                                    int* __restrict__ rowptr,
                                                    int* __restrict__ partials) {
    __shared__ int a[256], b[256];
    int t = threadIdx.x;
    int idx = blockIdx.x * 256 + t;
    int c = (idx < N_NODES) ? counts[idx] : 0;
    a[t] = c;
    __syncthreads();
    int* src = a; int* dst = b;
    for (int off = 1; off < 256; off <<= 1) {
        dst[t] = src[t] + ((t >= off) ? src[t - off] : 0);
        __syncthreads();
        int* tmp = src; src = dst; dst = tmp;
    }
    if (idx < N_NODES) rowptr[idx] = src[t] - c;   // exclusive within block
    if (t == 255) partials[blockIdx.x] = src[255];
}

// ---- CSR step 2b: scan the 196 block totals (exclusive) ----
__global__ __launch_bounds__(256) void k_scan_part(int* __restrict__ partials) {
    __shared__ int a[256], b[256];
    int t = threadIdx.x;
    int c = (t < SCAN_NB) ? partials[t] : 0;
    a[t] = c;
    __syncthreads();
    int* src = a; int* dst = b;
    for (int off = 1; off < 256; off <<= 1) {
        dst[t] = src[t] + ((t >= off) ? src[t - off] : 0);
        __syncthreads();
        int* tmp = src; src = dst; dst = tmp;
    }
    if (t < SCAN_NB) partials[t] = src[t] - c;     // exclusive
}

// ---- CSR step 2c: add block prefix; mirror to cursor; cap rowptr ----
__global__ void k_scan_add(int* __restrict__ rowptr, int* __restrict__ cursor,
                           const int* __restrict__ partials) {
    int idx = blockIdx.x * 256 + threadIdx.x;
    if (idx < N_NODES) {
        int v = rowptr[idx] + partials[blockIdx.x];
        rowptr[idx] = v;
        cursor[idx] = v;
    } else if (idx == N_NODES) {
        rowptr[N_NODES] = N_EDGES;   // all (clamped) edges are counted
    }
}

// ---- CSR step 3: fill buckets with src ids ----
__global__ void k_fill(const int* __restrict__ ei, int* __restrict__ cursor,
                       int* __restrict__ bucket, const int* __restrict__ flags) {
    int i64 = flags[1];
    int e = blockIdx.x * 256 + threadIdx.x;
    int s, d;
    if (i64) { s = ei[2 * e]; d = ei[2 * N_EDGES + 2 * e]; }
    else     { s = ei[e];     d = ei[N_EDGES + e]; }
    s = min(max(s, 0), N_NODES - 1);
    d = min(max(d, 0), N_NODES - 1);
    int pos = atomicAdd(&cursor[d], 1);
    bucket[pos] = s;
}

// ---- gather-sum: agg[row] = x[row] + sum_{e:dst=row} x[src[e]]; pad rows = 0 ----
__global__ __launch_bounds__(256) void k_gather(const int* __restrict__ rowptr,
                                                const int* __restrict__ bucket,
                                                const void* __restrict__ x,
                                                float* __restrict__ agg,
                                                const int* __restrict__ flags) {
    int isf = flags[0];
    int w = threadIdx.x >> 6, lane = threadIdx.x & 63;
    int row = blockIdx.x * 4 + w;          // grid = NPAD/4, exact
    float a0 = 0.f, a1 = 0.f;
    if (row < N_NODES) {
        int beg = rowptr[row], end = rowptr[row + 1];
        if (isf) {
            float2 v = *(const float2*)((const float*)x + (size_t)row * D_IN + lane * 2);
            a0 = v.x; a1 = v.y;
            for (int j = beg; j < end; j++) {
                int s = bucket[j];
                float2 n = *(const float2*)((const float*)x + (size_t)s * D_IN + lane * 2);
                a0 += n.x; a1 += n.y;
            }
        } else {
            unsigned int u = ((const unsigned int*)x)[(size_t)row * 64 + lane];
            a0 = bf2f(u & 0xffff); a1 = bf2f(u >> 16);
            for (int j = beg; j < end; j++) {
                int s = bucket[j];
                unsigned int n = ((const unsigned int*)x)[(size_t)s * 64 + lane];
                a0 += bf2f(n & 0xffff); a1 += bf2f(n >> 16);
            }
        }
    }
    *(float2*)(agg + (size_t)row * D_IN + lane * 2) = make_float2(a0, a1);
}

// ---- pass A: GEMM1 column stats (X tile staged once, loop 4 W-tiles) ----
__global__ __launch_bounds__(256) void k_g1stats(const float* __restrict__ agg,
                                                 const unsigned short* __restrict__ w1t,
                                                 const void* __restrict__ b1,
                                                 float* __restrict__ sum1,
                                                 float* __restrict__ sumsq1,
                                                 const int* __restrict__ flags) {
    __shared__ unsigned short ldsX[128 * 128];
    __shared__ unsigned short ldsW[128 * 128];
    int isf = flags[0];
    int t = threadIdx.x;
    int m0 = blockIdx.x * 128;
    int r = t >> 1, half = t & 1;
#pragma unroll
    for (int i = 0; i < 8; i++) {
        int chunk = half * 8 + i;
        int sw = ((chunk ^ (r & 15)) * 8);
        const float* g = agg + (size_t)(m0 + r) * D_IN + chunk * 8;
        *(uint4*)(ldsX + r * 128 + sw) = pack8(*(const float4*)g, *(const float4*)(g + 4));
    }
    int wid = t >> 6, lane = t & 63;
    int wm = wid & 1, wn = wid >> 1;
    int quad = lane >> 4, l16 = lane & 15;
    for (int nb = 0; nb < 4; nb++) {
        __syncthreads();   // X staged / prior W readers done
#pragma unroll
        for (int i = 0; i < 8; i++) {
            int chunk = half * 8 + i;
            *(uint4*)(ldsW + r * 128 + ((chunk ^ (r & 15)) * 8)) =
                *(const uint4*)(w1t + (size_t)(nb * 128 + r) * D_IN + chunk * 8);
        }
        __syncthreads();
        f32x4 acc[4][4] = {};
#pragma unroll
        for (int ks = 0; ks < 4; ks++) {
            short8 af[4], bfr[4];
#pragma unroll
            for (int mt = 0; mt < 4; mt++)
                af[mt] = *(const short8*)(ldsX + (wm * 64 + mt * 16 + l16) * 128 + (((ks * 4 + quad) ^ l16) * 8));
#pragma unroll
            for (int nt = 0; nt < 4; nt++)
                bfr[nt] = *(const short8*)(ldsW + (wn * 64 + nt * 16 + l16) * 128 + (((ks * 4 + quad) ^ l16) * 8));
#pragma unroll
            for (int mt = 0; mt < 4; mt++)
#pragma unroll
                for (int nt = 0; nt < 4; nt++)
                    acc[mt][nt] = __builtin_amdgcn_mfma_f32_16x16x32_bf16(af[mt], bfr[nt], acc[mt][nt], 0, 0, 0);
        }
#pragma unroll
        for (int nt = 0; nt < 4; nt++) {
            int n = nb * 128 + wn * 64 + nt * 16 + l16;
            float bias = loadP(b1, n, isf);
            float s = 0.f, ss = 0.f;
#pragma unroll
            for (int mt = 0; mt < 4; mt++) {
                int Rb = m0 + wm * 64 + mt * 16 + quad * 4;
#pragma unroll
                for (int rg = 0; rg < 4; rg++) {
                    if (Rb + rg < N_NODES) {
                        float z = acc[mt][nt][rg] + bias;
                        s += z; ss += z * z;
                    }
                }
            }
            s += __shfl_xor(s, 16, 64); ss += __shfl_xor(ss, 16, 64);
            s += __shfl_xor(s, 32, 64); ss += __shfl_xor(ss, 32, 64);
            if (quad == 0) { atomicAdd(&sum1[n], s); atomicAdd(&sumsq1[n], ss); }
        }
    }
}

// ---- pass B: fused GEMM1 -> BN1+ReLU -> GEMM2 (+b2), h2 f32, BN2 stats fused ----
__global__ __launch_bounds__(256) void k_fused(const float* __restrict__ agg,
                                               const unsigned short* __restrict__ w1t,
                                               const unsigned short* __restrict__ w2t,
                                               const void* __restrict__ b1,
                                               const void* __restrict__ b2,
                                               const void* __restrict__ g1,
                                               const void* __restrict__ bb1,
                                               const float* __restrict__ sum1,
                                               const float* __restrict__ sumsq1,
                                               float* __restrict__ h2,
                                               float* __restrict__ sum2,
                                               float* __restrict__ sumsq2,
                                               const int* __restrict__ flags) {
    __shared__ unsigned short bufXP[128 * 128];
    __shared__ unsigned short bufW[128 * 128];
    int isf = flags[0];
    int t = threadIdx.x;
    int m0 = blockIdx.x * 128;
    int r = t >> 1, half = t & 1;
    int wid = t >> 6, lane = t & 63;
    int wm = wid & 1, wn = wid >> 1;
    int quad = lane >> 4, l16 = lane & 15;
    f32x4 acc2[4][4] = {};
    for (int nb = 0; nb < 4; nb++) {
        __syncthreads();
#pragma unroll
        for (int i = 0; i < 8; i++) {
            int chunk = half * 8 + i;
            int sw = ((chunk ^ (r & 15)) * 8);
            const float* g = agg + (size_t)(m0 + r) * D_IN + chunk * 8;
            *(uint4*)(bufXP + r * 128 + sw) = pack8(*(const float4*)g, *(const float4*)(g + 4));
            *(uint4*)(bufW + r * 128 + sw) = *(const uint4*)(w1t + (size_t)(nb * 128 + r) * D_IN + chunk * 8);
        }
        __syncthreads();
        f32x4 acc1[4][4] = {};
#pragma unroll
        for (int ks = 0; ks < 4; ks++) {
            short8 af[4], bfr[4];
#pragma unroll
            for (int mt = 0; mt < 4; mt++)
                af[mt] = *(const short8*)(bufXP + (wm * 64 + mt * 16 + l16) * 128 + (((ks * 4 + quad) ^ l16) * 8));
#pragma unroll
            for (int nt = 0; nt < 4; nt++)
                bfr[nt] = *(const short8*)(bufW + (wn * 64 + nt * 16 + l16) * 128 + (((ks * 4 + quad) ^ l16) * 8));
#pragma unroll
            for (int mt = 0; mt < 4; mt++)
#pragma unroll
                for (int nt = 0; nt < 4; nt++)
                    acc1[mt][nt] = __builtin_amdgcn_mfma_f32_16x16x32_bf16(af[mt], bfr[nt], acc1[mt][nt], 0, 0, 0);
        }
        __syncthreads();
#pragma unroll
        for (int nt = 0; nt < 4; nt++) {
            int nl = wn * 64 + nt * 16 + l16;
            int n1 = nb * 128 + nl;
            float mz = sum1[n1] * (1.f / N_NODES);
            float vz = sumsq1[n1] * (1.f / N_NODES) - mz * mz;
            float inv = rsqrtf(fmaxf(vz, 0.f) + 1e-5f);
            float A = loadP(g1, n1, isf) * inv;
            float C = loadP(bb1, n1, isf) - mz * A + loadP(b1, n1, isf) * A;
            int ccw = nl >> 3, cl = nl & 7;
#pragma unroll
            for (int mt = 0; mt < 4; mt++)
#pragma unroll
                for (int rg = 0; rg < 4; rg++) {
                    int R = wm * 64 + mt * 16 + quad * 4 + rg;
                    float z = fmaxf(acc1[mt][nt][rg] * A + C, 0.f);
                    bufXP[R * 128 + ((ccw ^ (R & 15)) * 8) + cl] = f2bf(z);
                }
        }
#pragma unroll
        for (int i = 0; i < 8; i++) {
            int chunk = half * 8 + i;
            *(uint4*)(bufW + r * 128 + ((chunk ^ (r & 15)) * 8)) =
                *(const uint4*)(w2t + (size_t)r * D_HID + nb * 128 + chunk * 8);
        }
        __syncthreads();
#pragma unroll
        for (int ks = 0; ks < 4; ks++) {
            short8 af[4], bfr[4];
#pragma unroll
            for (int mt = 0; mt < 4; mt++)
                af[mt] = *(const short8*)(bufXP + (wm * 64 + mt * 16 + l16) * 128 + (((ks * 4 + quad) ^ l16) * 8));
#pragma unroll
            for (int nt = 0; nt < 4; nt++)
                bfr[nt] = *(const short8*)(bufW + (wn * 64 + nt * 16 + l16) * 128 + (((ks * 4 + quad) ^ l16) * 8));
#pragma unroll
            for (int mt = 0; mt < 4; mt++)
#pragma unroll
                for (int nt = 0; nt < 4; nt++)
                    acc2[mt][nt] = __builtin_amdgcn_mfma_f32_16x16x32_bf16(af[mt], bfr[nt], acc2[mt][nt], 0, 0, 0);
        }
    }
#pragma unroll
    for (int nt = 0; nt < 4; nt++) {
        int n = wn * 64 + nt * 16 + l16;
        float bias = loadP(b2, n, isf);
        float s = 0.f, ss = 0.f;
#pragma unroll
        for (int mt = 0; mt < 4; mt++) {
            int Rb = m0 + wm * 64 + mt * 16 + quad * 4;
#pragma unroll
            for (int rg = 0; rg < 4; rg++) {
                float z = acc2[mt][nt][rg] + bias;
                h2[(size_t)(Rb + rg) * D_IN + n] = z;
                if (Rb + rg < N_NODES) { s += z; ss += z * z; }
            }
        }
        s += __shfl_xor(s, 16, 64); ss += __shfl_xor(ss, 16, 64);
        s += __shfl_xor(s, 32, 64); ss += __shfl_xor(ss, 32, 64);
        if (quad == 0) { atomicAdd(&sum2[n], s); atomicAdd(&sumsq2[n], ss); }
    }
}

// ---- BN2 + ReLU + residual + LayerNorm -> out ----
__global__ __launch_bounds__(256) void k_final(const float* __restrict__ h2,
                                               const void* __restrict__ x,
                                               const float* __restrict__ sum2,
                                               const float* __restrict__ sumsq2,
                                               const void* __restrict__ g2,
                                               const void* __restrict__ bb2,
                                               const void* __restrict__ lng,
                                               const void* __restrict__ lnb,
                                               void* __restrict__ out,
                                               const int* __restrict__ flags) {
    int isf = flags[0];
    __shared__ float a2s[D_IN], c2s[D_IN];
    int t = threadIdx.x;
    if (t < D_IN) {
        float m = sum2[t] * (1.f / N_NODES);
        float v = sumsq2[t] * (1.f / N_NODES) - m * m;
        float inv = rsqrtf(fmaxf(v, 0.f) + 1e-5f);
        float a = loadP(g2, t, isf) * inv;
        a2s[t] = a;
        c2s[t] = loadP(bb2, t, isf) - m * a;
    }
    __syncthreads();
    int w = t >> 6, lane = t & 63;
    int row = blockIdx.x * 4 + w;
    if (row >= N_NODES) return;
    size_t base = (size_t)row * D_IN;
    float o0 = fmaxf(a2s[lane] * h2[base + lane] + c2s[lane], 0.f) + loadP(x, base + lane, isf);
    float o1 = fmaxf(a2s[lane + 64] * h2[base + 64 + lane] + c2s[lane + 64], 0.f) + loadP(x, base + 64 + lane, isf);
    float s = o0 + o1, ss = o0 * o0 + o1 * o1;
#pragma unroll
    for (int m = 1; m < 64; m <<= 1) {
        s += __shfl_xor(s, m, 64);
        ss += __shfl_xor(ss, m, 64);
    }
    float mean = s * (1.f / D_IN);
    float var = ss * (1.f / D_IN) - mean * mean;
    float inv = rsqrtf(fmaxf(var, 0.f) + 1e-5f);
    float r0 = (o0 - mean) * inv * loadP(lng, lane, isf) + loadP(lnb, lane, isf);
    float r1 = (o1 - mean) * inv * loadP(lng, lane + 64, isf) + loadP(lnb, lane + 64, isf);
    if (isf) {
        ((float*)out)[base + lane] = r0;
        ((float*)out)[base + 64 + lane] = r1;
    } else {
        ((unsigned short*)out)[base + lane] = f2bf(r0);
        ((unsigned short*)out)[base + 64 + lane] = f2bf(r1);
    }
}

extern "C" void kernel_launch(void* const* d_in, const int* in_sizes, int n_in,
                              void* d_out, int out_size, void* d_ws, size_t ws_size,
                              hipStream_t stream) {
    const void* x    = d_in[0];
    const int*  ei   = (const int*)d_in[1];
    const void* W1   = d_in[2];
    const void* b1   = d_in[3];
    const void* bn1g = d_in[4];
    const void* bn1b = d_in[5];
    const void* W2   = d_in[6];
    const void* b2   = d_in[7];
    const void* bn2g = d_in[8];
    const void* bn2b = d_in[9];
    const void* lng  = d_in[10];
    const void* lnb  = d_in[11];

    // workspace layout (~28.2 MB)
    char* ws = (char*)d_ws;
    float* stats    = (float*)ws;                     // 1280 f32
    float* sum1     = stats;
    float* sumsq1   = stats + 512;
    float* sum2     = stats + 1024;
    float* sumsq2   = stats + 1152;
    int*   flags    = (int*)(ws + 5120);              // 2 ints
    int*   partials = (int*)(ws + 5184);              // 256 ints
    int*   rowptr   = (int*)(ws + 8192);              // 50001 ints
    int*   cursor   = (int*)(ws + 212992);            // 50000 ints (counts, then cursor)
    unsigned short* w1t = (unsigned short*)(ws + 417792);   // [512][128] bf16
    unsigned short* w2t = (unsigned short*)(ws + 548864);   // [128][512] bf16
    int*   bucket = (int*)(ws + 679936);              // 800000 ints
    float* agg    = (float*)(ws + 3879936);           // NPAD*128 f32, reused as h2
    float* h2     = agg;

    k_detect<<<1, 256, 0, stream>>>(x, ei, flags);
    k_zero<<<(1280 + N_NODES + 255) / 256, 256, 0, stream>>>(stats, cursor);
    k_transpose<<<256, 256, 0, stream>>>(W1, w1t, D_IN, D_HID, flags);
    k_transpose<<<256, 256, 0, stream>>>(W2, w2t, D_HID, D_IN, flags);
    k_count<<<N_EDGES / 256, 256, 0, stream>>>(ei, cursor, flags);
    k_scan_block<<<SCAN_NB, 256, 0, stream>>>(cursor, rowptr, partials);
    k_scan_part<<<1, 256, 0, stream>>>(partials);
    k_scan_add<<<SCAN_NB, 256, 0, stream>>>(rowptr, cursor, partials);
    k_fill<<<N_EDGES / 256, 256, 0, stream>>>(ei, cursor, bucket, flags);
    k_gather<<<NPAD / 4, 256, 0, stream>>>(rowptr, bucket, x, agg, flags);
    k_g1stats<<<NPAD / 128, 256, 0, stream>>>(agg, w1t, b1, sum1, sumsq1, flags);
    k_fused<<<NPAD / 128, 256, 0, stream>>>(agg, w1t, w2t, b1, b2, bn1g, bn1b,
                                            sum1, sumsq1, h2, sum2, sumsq2, flags);
    k_final<<<(N_NODES + 3) / 4, 256, 0, stream>>>(h2, x, sum2, sumsq2, bn2g, bn2b, lng, lnb, d_out, flags);
}

// Round 6
// 383.259 us; speedup vs baseline: 4.3449x; 1.0755x over previous
//
#include <hip/hip_runtime.h>
#include <stdint.h>

#define N_NODES 50000
#define N_EDGES 800000
#define D_IN    128
#define D_HID   512
#define NPAD    50048   // 391 * 128
#define SCAN_NB 196     // ceil(50000/256)

typedef __attribute__((ext_vector_type(8))) short short8;
typedef __attribute__((ext_vector_type(4))) float f32x4;

union Pack8 { unsigned short us[8]; uint4 v; };

__device__ __forceinline__ float bf2f(unsigned short u) {
    union { unsigned int i; float f; } v; v.i = ((unsigned int)u) << 16; return v.f;
}
__device__ __forceinline__ unsigned short f2bf(float f) {
    union { float f; unsigned int i; } v; v.f = f;
    unsigned int r = v.i + 0x7fffu + ((v.i >> 16) & 1u);
    return (unsigned short)(r >> 16);
}
__device__ __forceinline__ float loadP(const void* p, long i, int isf) {
    return isf ? ((const float*)p)[i] : bf2f(((const unsigned short*)p)[i]);
}
__device__ __forceinline__ uint4 pack8(float4 f0, float4 f1) {
    Pack8 p;
    p.us[0] = f2bf(f0.x); p.us[1] = f2bf(f0.y); p.us[2] = f2bf(f0.z); p.us[3] = f2bf(f0.w);
    p.us[4] = f2bf(f1.x); p.us[5] = f2bf(f1.y); p.us[6] = f2bf(f1.z); p.us[7] = f2bf(f1.w);
    return p.v;
}

// ---- fused: zero stats+counts (blocks 0..200) + detect flags (block 201) ----
__global__ void k_init(const void* __restrict__ x, const int* __restrict__ ei,
                       float* __restrict__ stats, int* __restrict__ counts,
                       int* __restrict__ flags) {
    int t = threadIdx.x;
    if (blockIdx.x < 201) {
        int i = blockIdx.x * 256 + t;
        if (i < 1280) stats[i] = 0.f;
        else if (i < 1280 + N_NODES) counts[i - 1280] = 0;
    } else {
        __shared__ int sh[2];
        if (t == 0) { sh[0] = 0; sh[1] = 1; }
        __syncthreads();
        const unsigned short* xu = (const unsigned short*)x;
        for (int i = t; i < 8192; i += 256)
            if (((xu[i] >> 7) & 0xFF) == 0xFF) sh[0] = 1;   // benign race
        for (int k = t; k < 64; k += 256)
            if (ei[2 * k + 1] != 0) sh[1] = 0;
        __syncthreads();
        if (t == 0) { flags[0] = sh[0]; flags[1] = sh[1]; }
    }
}

// ---- both weight transposes in one kernel ----
__global__ void k_transpose2(const void* __restrict__ W1, const void* __restrict__ W2,
                             unsigned short* __restrict__ w1t, unsigned short* __restrict__ w2t,
                             const int* __restrict__ flags) {
    int isf = flags[0];
    int idx = blockIdx.x * 256 + threadIdx.x;     // 512 blocks, 131072 threads
    if (idx < D_IN * D_HID) {
        int k = idx / D_HID, n = idx % D_HID;     // W1[k][n] -> w1t[n][k]
        w1t[n * D_IN + k] = isf ? f2bf(((const float*)W1)[idx])
                                : ((const unsigned short*)W1)[idx];
    } else {
        int j = idx - D_IN * D_HID;
        int k = j / D_IN, n = j % D_IN;           // W2[k][n] -> w2t[n][k]
        w2t[n * D_HID + k] = isf ? f2bf(((const float*)W2)[j])
                                 : ((const unsigned short*)W2)[j];
    }
}

// ---- CSR step 1: count in-degree ----
__global__ void k_count(const int* __restrict__ ei, int* __restrict__ counts,
                        const int* __restrict__ flags) {
    int i64 = flags[1];
    int e = blockIdx.x * 256 + threadIdx.x;
    int d = i64 ? ei[2 * N_EDGES + 2 * e] : ei[N_EDGES + e];
    d = min(max(d, 0), N_NODES - 1);
    atomicAdd(&counts[d], 1);
}

// ---- CSR step 2a: per-block exclusive scan; block sums -> partials ----
__global__ __launch_bounds__(256) void k_scan_block(const int* __restrict__ counts,
                                                    int* __restrict__ rowptr,
                                                    int* __restrict__ partials) {
    __shared__ int a[256], b[256];
    int t = threadIdx.x;
    int idx = blockIdx.x * 256 + t;
    int c = (idx < N_NODES) ? counts[idx] : 0;
    a[t] = c;
    __syncthreads();
    int* src = a; int* dst = b;
    for (int off = 1; off < 256; off <<= 1) {
        dst[t] = src[t] + ((t >= off) ? src[t - off] : 0);
        __syncthreads();
        int* tmp = src; src = dst; dst = tmp;
    }
    if (idx < N_NODES) rowptr[idx] = src[t] - c;
    if (t == 255) partials[blockIdx.x] = src[255];
}

// ---- CSR step 2b: scan the 196 block totals (exclusive) ----
__global__ __launch_bounds__(256) void k_scan_part(int* __restrict__ partials) {
    __shared__ int a[256], b[256];
    int t = threadIdx.x;
    int c = (t < SCAN_NB) ? partials[t] : 0;
    a[t] = c;
    __syncthreads();
    int* src = a; int* dst = b;
    for (int off = 1; off < 256; off <<= 1) {
        dst[t] = src[t] + ((t >= off) ? src[t - off] : 0);
        __syncthreads();
        int* tmp = src; src = dst; dst = tmp;
    }
    if (t < SCAN_NB) partials[t] = src[t] - c;
}

// ---- CSR step 2c: add block prefix; mirror to cursor; cap rowptr ----
__global__ void k_scan_add(int* __restrict__ rowptr, int* __restrict__ cursor,
                           const int* __restrict__ partials) {
    int idx = blockIdx.x * 256 + threadIdx.x;
    if (idx < N_NODES) {
        int v = rowptr[idx] + partials[blockIdx.x];
        rowptr[idx] = v;
        cursor[idx] = v;
    } else if (idx == N_NODES) {
        rowptr[N_NODES] = N_EDGES;
    }
}

// ---- CSR step 3: fill buckets with src ids ----
__global__ void k_fill(const int* __restrict__ ei, int* __restrict__ cursor,
                       int* __restrict__ bucket, const int* __restrict__ flags) {
    int i64 = flags[1];
    int e = blockIdx.x * 256 + threadIdx.x;
    int s, d;
    if (i64) { s = ei[2 * e]; d = ei[2 * N_EDGES + 2 * e]; }
    else     { s = ei[e];     d = ei[N_EDGES + e]; }
    s = min(max(s, 0), N_NODES - 1);
    d = min(max(d, 0), N_NODES - 1);
    int pos = atomicAdd(&cursor[d], 1);
    bucket[pos] = s;
}

// ---- gather-sum, 4-way ILP: agg[row] = x[row] + sum x[src]; pad rows = 0 ----
__global__ __launch_bounds__(256) void k_gather(const int* __restrict__ rowptr,
                                                const int* __restrict__ bucket,
                                                const void* __restrict__ x,
                                                float* __restrict__ agg,
                                                const int* __restrict__ flags) {
    int isf = flags[0];
    int w = threadIdx.x >> 6, lane = threadIdx.x & 63;
    int row = blockIdx.x * 4 + w;          // grid = NPAD/4, exact
    float a0 = 0.f, a1 = 0.f;
    if (row < N_NODES) {
        int beg = rowptr[row], end = rowptr[row + 1];
        if (isf) {
            const float* xf = (const float*)x;
            float2 v = *(const float2*)(xf + (size_t)row * D_IN + lane * 2);
            a0 = v.x; a1 = v.y;
            int j = beg;
            for (; j + 4 <= end; j += 4) {
                int s0 = bucket[j], s1 = bucket[j + 1], s2 = bucket[j + 2], s3 = bucket[j + 3];
                float2 n0 = *(const float2*)(xf + (size_t)s0 * D_IN + lane * 2);
                float2 n1 = *(const float2*)(xf + (size_t)s1 * D_IN + lane * 2);
                float2 n2 = *(const float2*)(xf + (size_t)s2 * D_IN + lane * 2);
                float2 n3 = *(const float2*)(xf + (size_t)s3 * D_IN + lane * 2);
                a0 += (n0.x + n1.x) + (n2.x + n3.x);
                a1 += (n0.y + n1.y) + (n2.y + n3.y);
            }
            for (; j < end; j++) {
                float2 n = *(const float2*)(xf + (size_t)bucket[j] * D_IN + lane * 2);
                a0 += n.x; a1 += n.y;
            }
        } else {
            const unsigned int* xu = (const unsigned int*)x;
            unsigned int u = xu[(size_t)row * 64 + lane];
            a0 = bf2f(u & 0xffff); a1 = bf2f(u >> 16);
            int j = beg;
            for (; j + 4 <= end; j += 4) {
                int s0 = bucket[j], s1 = bucket[j + 1], s2 = bucket[j + 2], s3 = bucket[j + 3];
                unsigned int u0 = xu[(size_t)s0 * 64 + lane];
                unsigned int u1 = xu[(size_t)s1 * 64 + lane];
                unsigned int u2 = xu[(size_t)s2 * 64 + lane];
                unsigned int u3 = xu[(size_t)s3 * 64 + lane];
                a0 += (bf2f(u0 & 0xffff) + bf2f(u1 & 0xffff)) + (bf2f(u2 & 0xffff) + bf2f(u3 & 0xffff));
                a1 += (bf2f(u0 >> 16) + bf2f(u1 >> 16)) + (bf2f(u2 >> 16) + bf2f(u3 >> 16));
            }
            for (; j < end; j++) {
                unsigned int n = xu[(size_t)bucket[j] * 64 + lane];
                a0 += bf2f(n & 0xffff); a1 += bf2f(n >> 16);
            }
        }
    }
    *(float2*)(agg + (size_t)row * D_IN + lane * 2) = make_float2(a0, a1);
}

// ---- pass A: GEMM1 column stats (X tile staged once, loop 4 W-tiles) ----
__global__ __launch_bounds__(256) void k_g1stats(const float* __restrict__ agg,
                                                 const unsigned short* __restrict__ w1t,
                                                 const void* __restrict__ b1,
                                                 float* __restrict__ sum1,
                                                 float* __restrict__ sumsq1,
                                                 const int* __restrict__ flags) {
    __shared__ unsigned short ldsX[128 * 128];
    __shared__ unsigned short ldsW[128 * 128];
    int isf = flags[0];
    int t = threadIdx.x;
    int m0 = blockIdx.x * 128;
    int r = t >> 1, half = t & 1;
#pragma unroll
    for (int i = 0; i < 8; i++) {
        int chunk = half * 8 + i;
        int sw = ((chunk ^ (r & 15)) * 8);
        const float* g = agg + (size_t)(m0 + r) * D_IN + chunk * 8;
        *(uint4*)(ldsX + r * 128 + sw) = pack8(*(const float4*)g, *(const float4*)(g + 4));
    }
    int wid = t >> 6, lane = t & 63;
    int wm = wid & 1, wn = wid >> 1;
    int quad = lane >> 4, l16 = lane & 15;
    for (int nb = 0; nb < 4; nb++) {
        __syncthreads();
#pragma unroll
        for (int i = 0; i < 8; i++) {
            int chunk = half * 8 + i;
            *(uint4*)(ldsW + r * 128 + ((chunk ^ (r & 15)) * 8)) =
                *(const uint4*)(w1t + (size_t)(nb * 128 + r) * D_IN + chunk * 8);
        }
        __syncthreads();
        f32x4 acc[4][4] = {};
#pragma unroll
        for (int ks = 0; ks < 4; ks++) {
            short8 af[4], bfr[4];
#pragma unroll
            for (int mt = 0; mt < 4; mt++)
                af[mt] = *(const short8*)(ldsX + (wm * 64 + mt * 16 + l16) * 128 + (((ks * 4 + quad) ^ l16) * 8));
#pragma unroll
            for (int nt = 0; nt < 4; nt++)
                bfr[nt] = *(const short8*)(ldsW + (wn * 64 + nt * 16 + l16) * 128 + (((ks * 4 + quad) ^ l16) * 8));
#pragma unroll
            for (int mt = 0; mt < 4; mt++)
#pragma unroll
                for (int nt = 0; nt < 4; nt++)
                    acc[mt][nt] = __builtin_amdgcn_mfma_f32_16x16x32_bf16(af[mt], bfr[nt], acc[mt][nt], 0, 0, 0);
        }
#pragma unroll
        for (int nt = 0; nt < 4; nt++) {
            int n = nb * 128 + wn * 64 + nt * 16 + l16;
            float bias = loadP(b1, n, isf);
            float s = 0.f, ss = 0.f;
#pragma unroll
            for (int mt = 0; mt < 4; mt++) {
                int Rb = m0 + wm * 64 + mt * 16 + quad * 4;
#pragma unroll
                for (int rg = 0; rg < 4; rg++) {
                    if (Rb + rg < N_NODES) {
                        float z = acc[mt][nt][rg] + bias;
                        s += z; ss += z * z;
                    }
                }
            }
            s += __shfl_xor(s, 16, 64); ss += __shfl_xor(ss, 16, 64);
            s += __shfl_xor(s, 32, 64); ss += __shfl_xor(ss, 32, 64);
            if (quad == 0) { atomicAdd(&sum1[n], s); atomicAdd(&sumsq1[n], ss); }
        }
    }
}

// ---- pass B: fused GEMM1 -> BN1+ReLU -> GEMM2 (+b2), h2 f32, BN2 stats fused ----
__global__ __launch_bounds__(256) void k_fused(const float* __restrict__ agg,
                                               const unsigned short* __restrict__ w1t,
                                               const unsigned short* __restrict__ w2t,
                                               const void* __restrict__ b1,
                                               const void* __restrict__ b2,
                                               const void* __restrict__ g1,
                                               const void* __restrict__ bb1,
                                               const float* __restrict__ sum1,
                                               const float* __restrict__ sumsq1,
                                               float* __restrict__ h2,
                                               float* __restrict__ sum2,
                                               float* __restrict__ sumsq2,
                                               const int* __restrict__ flags) {
    __shared__ unsigned short bufXP[128 * 128];
    __shared__ unsigned short bufW[128 * 128];
    int isf = flags[0];
    int t = threadIdx.x;
    int m0 = blockIdx.x * 128;
    int r = t >> 1, half = t & 1;
    int wid = t >> 6, lane = t & 63;
    int wm = wid & 1, wn = wid >> 1;
    int quad = lane >> 4, l16 = lane & 15;
    f32x4 acc2[4][4] = {};
    for (int nb = 0; nb < 4; nb++) {
        __syncthreads();
#pragma unroll
        for (int i = 0; i < 8; i++) {
            int chunk = half * 8 + i;
            int sw = ((chunk ^ (r & 15)) * 8);
            const float* g = agg + (size_t)(m0 + r) * D_IN + chunk * 8;
            *(uint4*)(bufXP + r * 128 + sw) = pack8(*(const float4*)g, *(const float4*)(g + 4));
            *(uint4*)(bufW + r * 128 + sw) = *(const uint4*)(w1t + (size_t)(nb * 128 + r) * D_IN + chunk * 8);
        }
        __syncthreads();
        f32x4 acc1[4][4] = {};
#pragma unroll
        for (int ks = 0; ks < 4; ks++) {
            short8 af[4], bfr[4];
#pragma unroll
            for (int mt = 0; mt < 4; mt++)
                af[mt] = *(const short8*)(bufXP + (wm * 64 + mt * 16 + l16) * 128 + (((ks * 4 + quad) ^ l16) * 8));
#pragma unroll
            for (int nt = 0; nt < 4; nt++)
                bfr[nt] = *(const short8*)(bufW + (wn * 64 + nt * 16 + l16) * 128 + (((ks * 4 + quad) ^ l16) * 8));
#pragma unroll
            for (int mt = 0; mt < 4; mt++)
#pragma unroll
                for (int nt = 0; nt < 4; nt++)
                    acc1[mt][nt] = __builtin_amdgcn_mfma_f32_16x16x32_bf16(af[mt], bfr[nt], acc1[mt][nt], 0, 0, 0);
        }
        __syncthreads();
#pragma unroll
        for (int nt = 0; nt < 4; nt++) {
            int nl = wn * 64 + nt * 16 + l16;
            int n1 = nb * 128 + nl;
            float mz = sum1[n1] * (1.f / N_NODES);
            float vz = sumsq1[n1] * (1.f / N_NODES) - mz * mz;
            float inv = rsqrtf(fmaxf(vz, 0.f) + 1e-5f);
            float A = loadP(g1, n1, isf) * inv;
            float C = loadP(bb1, n1, isf) - mz * A + loadP(b1, n1, isf) * A;
            int ccw = nl >> 3, cl = nl & 7;
#pragma unroll
            for (int mt = 0; mt < 4; mt++)
#pragma unroll
                for (int rg = 0; rg < 4; rg++) {
                    int R = wm * 64 + mt * 16 + quad * 4 + rg;
                    float z = fmaxf(acc1[mt][nt][rg] * A + C, 0.f);
                    bufXP[R * 128 + ((ccw ^ (R & 15)) * 8) + cl] = f2bf(z);
                }
        }
#pragma unroll
        for (int i = 0; i < 8; i++) {
            int chunk = half * 8 + i;
            *(uint4*)(bufW + r * 128 + ((chunk ^ (r & 15)) * 8)) =
                *(const uint4*)(w2t + (size_t)r * D_HID + nb * 128 + chunk * 8);
        }
        __syncthreads();
#pragma unroll
        for (int ks = 0; ks < 4; ks++) {
            short8 af[4], bfr[4];
#pragma unroll
            for (int mt = 0; mt < 4; mt++)
                af[mt] = *(const short8*)(bufXP + (wm * 64 + mt * 16 + l16) * 128 + (((ks * 4 + quad) ^ l16) * 8));
#pragma unroll
            for (int nt = 0; nt < 4; nt++)
                bfr[nt] = *(const short8*)(bufW + (wn * 64 + nt * 16 + l16) * 128 + (((ks * 4 + quad) ^ l16) * 8));
#pragma unroll
            for (int mt = 0; mt < 4; mt++)
#pragma unroll
                for (int nt = 0; nt < 4; nt++)
                    acc2[mt][nt] = __builtin_amdgcn_mfma_f32_16x16x32_bf16(af[mt], bfr[nt], acc2[mt][nt], 0, 0, 0);
        }
    }
#pragma unroll
    for (int nt = 0; nt < 4; nt++) {
        int n = wn * 64 + nt * 16 + l16;
        float bias = loadP(b2, n, isf);
        float s = 0.f, ss = 0.f;
#pragma unroll
        for (int mt = 0; mt < 4; mt++) {
            int Rb = m0 + wm * 64 + mt * 16 + quad * 4;
#pragma unroll
            for (int rg = 0; rg < 4; rg++) {
                float z = acc2[mt][nt][rg] + bias;
                h2[(size_t)(Rb + rg) * D_IN + n] = z;
                if (Rb + rg < N_NODES) { s += z; ss += z * z; }
            }
        }
        s += __shfl_xor(s, 16, 64); ss += __shfl_xor(ss, 16, 64);
        s += __shfl_xor(s, 32, 64); ss += __shfl_xor(ss, 32, 64);
        if (quad == 0) { atomicAdd(&sum2[n], s); atomicAdd(&sumsq2[n], ss); }
    }
}

// ---- BN2 + ReLU + residual + LayerNorm -> out ----
__global__ __launch_bounds__(256) void k_final(const float* __restrict__ h2,
                                               const void* __restrict__ x,
                                               const float* __restrict__ sum2,
                                               const float* __restrict__ sumsq2,
                                               const void* __restrict__ g2,
                                               const void* __restrict__ bb2,
                                               const void* __restrict__ lng,
                                               const void* __restrict__ lnb,
                                               void* __restrict__ out,
                                               const int* __restrict__ flags) {
    int isf = flags[0];
    __shared__ float a2s[D_IN], c2s[D_IN];
    int t = threadIdx.x;
    if (t < D_IN) {
        float m = sum2[t] * (1.f / N_NODES);
        float v = sumsq2[t] * (1.f / N_NODES) - m * m;
        float inv = rsqrtf(fmaxf(v, 0.f) + 1e-5f);
        float a = loadP(g2, t, isf) * inv;
        a2s[t] = a;
        c2s[t] = loadP(bb2, t, isf) - m * a;
    }
    __syncthreads();
    int w = t >> 6, lane = t & 63;
    int row = blockIdx.x * 4 + w;
    if (row >= N_NODES) return;
    size_t base = (size_t)row * D_IN;
    float o0 = fmaxf(a2s[lane] * h2[base + lane] + c2s[lane], 0.f) + loadP(x, base + lane, isf);
    float o1 = fmaxf(a2s[lane + 64] * h2[base + 64 + lane] + c2s[lane + 64], 0.f) + loadP(x, base + 64 + lane, isf);
    float s = o0 + o1, ss = o0 * o0 + o1 * o1;
#pragma unroll
    for (int m = 1; m < 64; m <<= 1) {
        s += __shfl_xor(s, m, 64);
        ss += __shfl_xor(ss, m, 64);
    }
    float mean = s * (1.f / D_IN);
    float var = ss * (1.f / D_IN) - mean * mean;
    float inv = rsqrtf(fmaxf(var, 0.f) + 1e-5f);
    float r0 = (o0 - mean) * inv * loadP(lng, lane, isf) + loadP(lnb, lane, isf);
    float r1 = (o1 - mean) * inv * loadP(lng, lane + 64, isf) + loadP(lnb, lane + 64, isf);
    if (isf) {
        ((float*)out)[base + lane] = r0;
        ((float*)out)[base + 64 + lane] = r1;
    } else {
        ((unsigned short*)out)[base + lane] = f2bf(r0);
        ((unsigned short*)out)[base + 64 + lane] = f2bf(r1);
    }
}

extern "C" void kernel_launch(void* const* d_in, const int* in_sizes, int n_in,
                              void* d_out, int out_size, void* d_ws, size_t ws_size,
                              hipStream_t stream) {
    const void* x    = d_in[0];
    const int*  ei   = (const int*)d_in[1];
    const void* W1   = d_in[2];
    const void* b1   = d_in[3];
    const void* bn1g = d_in[4];
    const void* bn1b = d_in[5];
    const void* W2   = d_in[6];
    const void* b2   = d_in[7];
    const void* bn2g = d_in[8];
    const void* bn2b = d_in[9];
    const void* lng  = d_in[10];
    const void* lnb  = d_in[11];

    // workspace layout (~28.2 MB)
    char* ws = (char*)d_ws;
    float* stats    = (float*)ws;                     // 1280 f32
    float* sum1     = stats;
    float* sumsq1   = stats + 512;
    float* sum2     = stats + 1024;
    float* sumsq2   = stats + 1152;
    int*   flags    = (int*)(ws + 5120);              // 2 ints
    int*   partials = (int*)(ws + 5184);              // 256 ints
    int*   rowptr   = (int*)(ws + 8192);              // 50001 ints
    int*   cursor   = (int*)(ws + 212992);            // 50000 ints (counts, then cursor)
    unsigned short* w1t = (unsigned short*)(ws + 417792);   // [512][128] bf16
    unsigned short* w2t = (unsigned short*)(ws + 548864);   // [128][512] bf16
    int*   bucket = (int*)(ws + 679936);              // 800000 ints
    float* agg    = (float*)(ws + 3879936);           // NPAD*128 f32, reused as h2
    float* h2     = agg;

    k_init<<<202, 256, 0, stream>>>(x, ei, stats, cursor, flags);
    k_transpose2<<<512, 256, 0, stream>>>(W1, W2, w1t, w2t, flags);
    k_count<<<N_EDGES / 256, 256, 0, stream>>>(ei, cursor, flags);
    k_scan_block<<<SCAN_NB, 256, 0, stream>>>(cursor, rowptr, partials);
    k_scan_part<<<1, 256, 0, stream>>>(partials);
    k_scan_add<<<SCAN_NB, 256, 0, stream>>>(rowptr, cursor, partials);
    k_fill<<<N_EDGES / 256, 256, 0, stream>>>(ei, cursor, bucket, flags);
    k_gather<<<NPAD / 4, 256, 0, stream>>>(rowptr, bucket, x, agg, flags);
    k_g1stats<<<NPAD / 128, 256, 0, stream>>>(agg, w1t, b1, sum1, sumsq1, flags);
    k_fused<<<NPAD / 128, 256, 0, stream>>>(agg, w1t, w2t, b1, b2, bn1g, bn1b,
                                            sum1, sumsq1, h2, sum2, sumsq2, flags);
    k_final<<<(N_NODES + 3) / 4, 256, 0, stream>>>(h2, x, sum2, sumsq2, bn2g, bn2b, lng, lnb, d_out, flags);
}